// Round 1
// baseline (276.863 us; speedup 1.0000x reference)
//
#include <hip/hip_runtime.h>

#define NPTS_C 32            // channels
#define NTAPS 27             // 3x3x3
#define KEY_WORDS (1u << 20) // 2^25 keys / 32 bits
#define SCAN_BLOCKS 1024     // KEY_WORDS / 1024 words per block

typedef float f32x4 __attribute__((ext_vector_type(4))); // native vec for nontemporal store

__device__ __forceinline__ unsigned make_key(int b, int x, int y, int z) {
    return ((((unsigned)b << 8 | (unsigned)x) << 8 | (unsigned)y) << 8) | (unsigned)z;
}

// 1) scatter occupancy bits
__global__ void k_scatter_bits(const int4* __restrict__ coords, unsigned* __restrict__ bitmask, int n) {
    int i = blockIdx.x * blockDim.x + threadIdx.x;
    if (i >= n) return;
    int4 co = coords[i];
    unsigned key = make_key(co.x, co.y, co.z, co.w);
    atomicOr(&bitmask[key >> 5], 1u << (key & 31u));
}

// 2) per-block (1024 words) popcount sums
__global__ void k_popc_sums(const uint4* __restrict__ bm4, unsigned* __restrict__ blockSums) {
    int t = threadIdx.x;
    uint4 w = bm4[blockIdx.x * 256 + t];
    unsigned s = __popc(w.x) + __popc(w.y) + __popc(w.z) + __popc(w.w);
    for (int off = 32; off > 0; off >>= 1) s += __shfl_down(s, off, 64);
    __shared__ unsigned wsum[4];
    if ((t & 63) == 0) wsum[t >> 6] = s;
    __syncthreads();
    if (t == 0) blockSums[blockIdx.x] = wsum[0] + wsum[1] + wsum[2] + wsum[3];
}

// 3) combined[word] = {bits, exclusive prefix popcount}
__global__ void k_build_combined(const uint4* __restrict__ bm4, const unsigned* __restrict__ blockSums,
                                 uint4* __restrict__ combined4) {
    int t = threadIdx.x, lane = t & 63;
    __shared__ unsigned preW[4];
    __shared__ unsigned wsum[4];

    unsigned pre = 0;
    for (int i = t; i < blockIdx.x; i += 256) pre += blockSums[i];
    for (int off = 32; off > 0; off >>= 1) pre += __shfl_down(pre, off, 64);
    if (lane == 0) preW[t >> 6] = pre;
    __syncthreads();
    unsigned blockBase = preW[0] + preW[1] + preW[2] + preW[3];

    int gw = blockIdx.x * 256 + t;
    uint4 w = bm4[gw];
    unsigned p0 = __popc(w.x), p1 = __popc(w.y), p2 = __popc(w.z), p3 = __popc(w.w);
    unsigned s = p0 + p1 + p2 + p3;
    unsigned incl = s;
    for (int off = 1; off < 64; off <<= 1) {
        unsigned u = __shfl_up(incl, off, 64);
        if (lane >= off) incl += u;
    }
    if (lane == 63) wsum[t >> 6] = incl;
    __syncthreads();
    unsigned waveBase = 0;
    int wv = t >> 6;
    for (int i = 0; i < wv; i++) waveBase += wsum[i];
    unsigned excl = blockBase + waveBase + incl - s;
    uint4 a; a.x = w.x; a.y = excl;           a.z = w.y; a.w = excl + p0;
    uint4 b; b.x = w.z; b.y = excl + p0 + p1; b.z = w.w; b.w = excl + p0 + p1 + p2;
    combined4[gw * 2 + 0] = a;
    combined4[gw * 2 + 1] = b;
}

__device__ __forceinline__ unsigned rank_of(unsigned key, const uint2* __restrict__ combined) {
    uint2 cw = combined[key >> 5];
    unsigned bit = key & 31u;
    return cw.y + __popc(cw.x & ((1u << bit) - 1u));
}

// 4) origOf[rank] = original index (4 B scatter)
__global__ void k_scatter_rank(const int4* __restrict__ coords, const uint2* __restrict__ combined,
                               int* __restrict__ origOf, int n) {
    int i = blockIdx.x * blockDim.x + threadIdx.x;
    if (i >= n) return;
    int4 co = coords[i];
    unsigned r = rank_of(make_key(co.x, co.y, co.z, co.w), combined);
    origOf[r] = i;
}

// 5) FUSED conv: reads feats directly via origOf (no sfeats pass).
//    4 points per 32-group, center-tap via myO captured in resolve rounds,
//    neighbor ranks translated rank->orig during resolve (parallel across tap lanes).
__global__ __launch_bounds__(256) void k_conv_fused4(const float* __restrict__ feats,
                                                     const float* __restrict__ weight,
                                                     const int4* __restrict__ coords,
                                                     const uint2* __restrict__ combined,
                                                     const int* __restrict__ origOf,
                                                     float* __restrict__ out,
                                                     float* __restrict__ outCoordsF, int n) {
    __shared__ float4 swT4[NTAPS * 9];   // swT4[kk*9+q] = weights for channels 4q..4q+3, tap kk (pad 8->9)
    __shared__ int ldsN[8][4][28];       // [group][round][tap] resolved ORIGINAL index or -1

    int t = threadIdx.x;
    for (int idx = t; idx < NTAPS * 8; idx += 256) {
        int kk = idx >> 3, q = idx & 7;
        float4 w4;
        w4.x = weight[(4 * q + 0) * NTAPS + kk];
        w4.y = weight[(4 * q + 1) * NTAPS + kk];
        w4.z = weight[(4 * q + 2) * NTAPS + kk];
        w4.w = weight[(4 * q + 3) * NTAPS + kk];
        swT4[kk * 9 + q] = w4;
    }

    int gi = t >> 5, l = t & 31;
    bool hi = (t & 32) != 0;
    int p0 = (blockIdx.x * 8 + gi) * 4;  // 4 consecutive ranks per group
    int cluster = l >> 3, q = l & 7;

    // lane constants (hoisted out of the 4 resolve rounds)
    int dxl = l / 9 - 1, dyl = (l % 9) / 3 - 1, dzl = l % 3 - 1;
    int jl = l / 3;                      // probing lane for tap l
    int pbx = l / 3 - 1, pby = l % 3 - 1; // probe (dx,dy) for lanes 0..8

    unsigned mk[4];
    int myO = 0;                         // orig index of this lane's cluster point
    #pragma unroll
    for (int r = 0; r < 4; r++) {
        int pc = min(p0 + r, n - 1);
        int o = origOf[pc];              // broadcast among 32 lanes
        if (r == cluster) myO = o;       // compile-time r: register select
        int4 co = coords[o];             // broadcast scattered 16B read
        int cb = co.x, cx = co.y, cy = co.z, cz = co.w;

        if (l == 0 && p0 + r < n) {      // emit sorted coords (near-coalesced 16B stores)
            float4 fc; fc.x = (float)cb; fc.y = (float)cx; fc.z = (float)cy; fc.w = (float)cz;
            ((float4*)outCoordsF)[pc] = fc;
        }

        uint2 cw; cw.x = 0u; cw.y = 0u;
        if (l < 9) {
            int xj = cx + pbx, yj = cy + pby;
            if ((unsigned)xj < 256u && (unsigned)yj < 256u)
                cw = combined[make_key(cb, xj, yj, cz) >> 5];
        }
        unsigned bb = __shfl(cw.x, jl, 32);
        unsigned pp = __shfl(cw.y, jl, 32);

        int x = cx + dxl, y = cy + dyl, z = cz + dzl;
        int nidx = -1;
        if (l < NTAPS && l != 13 &&
            (unsigned)x < 256u && (unsigned)y < 256u && (unsigned)z < 256u) {
            unsigned keyk = make_key(cb, x, y, z);
            if ((z >> 5) != (cz >> 5)) { // z crossed word boundary: self-probe
                uint2 t2 = combined[keyk >> 5];
                bb = t2.x; pp = t2.y;
            }
            unsigned bit = keyk & 31u;
            if ((bb >> bit) & 1u)
                nidx = (int)(pp + __popc(bb & ((1u << bit) - 1u)));
        }
        // rank -> original index, done here (parallel across tap lanes, overlapped
        // across rounds) so the accumulate loop keeps the same dependency depth.
        if (nidx >= 0) nidx = origOf[nidx]; // 4B read in 2.4MB L2-resident array
        unsigned long long bal = __ballot(nidx >= 0);
        mk[r] = hi ? (unsigned)(bal >> 32) : (unsigned)bal;
        if (l < NTAPS) ldsN[gi][r][l] = nidx;
    }
    __syncthreads(); // covers swT4 fill + ldsN writes

    int pm = p0 + cluster;
    float4 acc; acc.x = acc.y = acc.z = acc.w = 0.0f;
    if (pm < n) { // center tap: scattered 128B row read (2 lines, fully used)
        float4 f = ((const float4*)(feats + (size_t)myO * NPTS_C))[q];
        float4 w4 = swT4[13 * 9 + q];
        acc.x = f.x * w4.x; acc.y = f.y * w4.y; acc.z = f.z * w4.z; acc.w = f.w * w4.w;
    }

    unsigned m = mk[cluster]; // cluster-uniform mask, ~0.47 set bits avg
    while (m) {
        int kk = __ffs(m) - 1; m &= m - 1;
        int g = ldsN[gi][cluster][kk];                       // broadcast ds_read (orig index)
        float4 f = ((const float4*)(feats + (size_t)g * NPTS_C))[q]; // scattered 128B row
        float4 w4 = swT4[kk * 9 + q];
        acc.x += f.x * w4.x; acc.y += f.y * w4.y; acc.z += f.z * w4.z; acc.w += f.w * w4.w;
    }
    if (pm < n) {
        f32x4 v; v.x = acc.x; v.y = acc.y; v.z = acc.z; v.w = acc.w;
        f32x4* dst = (f32x4*)(out + (size_t)pm * NPTS_C);
        __builtin_nontemporal_store(v, &dst[q]);
    }
}

extern "C" void kernel_launch(void* const* d_in, const int* in_sizes, int n_in,
                              void* d_out, int out_size, void* d_ws, size_t ws_size,
                              hipStream_t stream) {
    const float* feats  = (const float*)d_in[0];
    const int4*  coords = (const int4*)d_in[1];
    const float* weight = (const float*)d_in[2];
    const int n = in_sizes[1] / 4;

    float* out        = (float*)d_out;              // [N, 32] f32
    float* outCoordsF = (float*)d_out + n * NPTS_C; // [N, 4] float values

    char* ws = (char*)d_ws;
    unsigned* bitmask   = (unsigned*)ws;                               // 4 MB (reused as origOf)
    uint2*    combined  = (uint2*)(ws + (size_t)KEY_WORDS * 4);        // 8 MB
    unsigned* blockSums = (unsigned*)(ws + (size_t)KEY_WORDS * 12);    // 4 KB

    int* origOf = (int*)bitmask; // bitmask dead after k_build_combined; N*4 <= 4 MB

    (void)hipMemsetAsync(bitmask, 0, (size_t)KEY_WORDS * 4, stream);

    int tb = 256;
    k_scatter_bits<<<(n + tb - 1) / tb, tb, 0, stream>>>(coords, bitmask, n);
    k_popc_sums<<<SCAN_BLOCKS, 256, 0, stream>>>((const uint4*)bitmask, blockSums);
    k_build_combined<<<SCAN_BLOCKS, 256, 0, stream>>>((const uint4*)bitmask, blockSums, (uint4*)combined);
    k_scatter_rank<<<(n + tb - 1) / tb, tb, 0, stream>>>(coords, combined, origOf, n);
    k_conv_fused4<<<(n + 31) / 32, 256, 0, stream>>>(feats, weight, coords, combined, origOf,
                                                     out, outCoordsF, n);
}